// Round 2
// baseline (193.440 us; speedup 1.0000x reference)
//
#include <hip/hip_runtime.h>
#include <hip/hip_bf16.h>
#include <math.h>

#define KCURV  0.1f
#define SQRT_K 0.31622776601683794f
#define INV_SQRT_K 3.1622776601683795f
#define TD 64   // feature dim D
#define BM 64   // batch rows per block
#define BN 64   // classes per block
#define LDP 68  // padded LDS row stride (floats), 272B = 16B aligned

__global__ __launch_bounds__(256) void hyper_mlr_kernel(
    const float* __restrict__ x,       // [B,64]
    const float* __restrict__ a_vals,  // [C,64]
    const float* __restrict__ p_vals,  // [C,64]
    float* __restrict__ out,           // [B,C] float32
    int B, int C)
{
    __shared__ float Xs[BM][LDP];   // [row][k]   raw x
    __shared__ float Ps[TD][LDP];   // [k][cls]   mp = -p_poin
    __shared__ float As[TD][LDP];   // [k][cls]   a_poin
    __shared__ float x2s[BN], pas[BN], ans[BN], scs[BN], y2s[BM];

    const int tid = threadIdx.x;
    const int cb = blockIdx.x * BN;
    const int rb = blockIdx.y * BM;

    // ---- stage 1: X tile global -> LDS (row-major, coalesced float4) ----
    for (int t = 0; t < 4; ++t) {
        int idx = t * 256 + tid;        // 0..1023 float4 slots (64 rows x 16)
        int row = idx >> 4;
        int c4  = idx & 15;
        int gr = rb + row; if (gr >= B) gr = B - 1;
        float4 v = *(const float4*)(x + (size_t)gr * TD + c4 * 4);
        *(float4*)&Xs[row][c4 * 4] = v;
    }

    // ---- stage 2: per-class hyperbolic transform (4 lanes per class) ----
    {
        int c = tid >> 2;           // local class 0..63
        int q = tid & 3;            // quarter of the D dimension
        int gc = cb + c; if (gc >= C) gc = C - 1;
        const float* pr = p_vals + (size_t)gc * TD + q * 16;
        const float* ar = a_vals + (size_t)gc * TD + q * 16;
        float4 pv[4], av[4];
        float s_pp = 0.f, s_aa = 0.f, s_pa = 0.f;
        for (int m = 0; m < 4; ++m) {
            pv[m] = *(const float4*)(pr + m * 4);
            av[m] = *(const float4*)(ar + m * 4);
            const float* pf = (const float*)&pv[m];
            const float* af = (const float*)&av[m];
            for (int u = 0; u < 4; ++u) {
                s_pp = fmaf(pf[u], pf[u], s_pp);
                s_aa = fmaf(af[u], af[u], s_aa);
                s_pa = fmaf(pf[u], af[u], s_pa);
            }
        }
        // reduce across the 4-lane group (lanes 4c+q, q=0..3)
        s_pp += __shfl_xor(s_pp, 1, 64); s_pp += __shfl_xor(s_pp, 2, 64);
        s_aa += __shfl_xor(s_aa, 1, 64); s_aa += __shfl_xor(s_aa, 2, 64);
        s_pa += __shfl_xor(s_pa, 1, 64); s_pa += __shfl_xor(s_pa, 2, 64);

        float pn = sqrtf(s_pp); if (pn < 1e-15f) pn = 1e-15f;
        float arg = SQRT_K * pn;
        float t = tanhf(arg);
        float factor = t / arg;                 // p_poin = factor * p
        float p2 = factor * factor * s_pp;      // ||p_poin||^2  (== x2)
        float ca = 1.0f + KCURV * p2;           // a_poin = ca * a
        float anorm = ca * sqrtf(s_aa); if (anorm < 1e-15f) anorm = 1e-15f;
        float pa = -factor * ca * s_pa;         // sum(mp * a_poin)
        float lam = 2.0f / (1.0f - KCURV * p2);
        float scale = lam * anorm * INV_SQRT_K;

        if (q == 0) { x2s[c] = p2; pas[c] = pa; ans[c] = anorm; scs[c] = scale; }

        // write transformed operands K-major for vectorized LDS reads
        for (int m = 0; m < 4; ++m) {
            const float* pf = (const float*)&pv[m];
            const float* af = (const float*)&av[m];
            for (int u = 0; u < 4; ++u) {
                int kk = q * 16 + m * 4 + u;
                Ps[kk][c] = -factor * pf[u];
                As[kk][c] = ca * af[u];
            }
        }
    }
    __syncthreads();

    // ---- stage 3: y2 per row (4 lanes per row, from LDS) ----
    {
        int r = tid >> 2, q = tid & 3;
        const float* xr = &Xs[r][q * 16];
        float s = 0.f;
        for (int u = 0; u < 16; ++u) s = fmaf(xr[u], xr[u], s);
        s += __shfl_xor(s, 1, 64);
        s += __shfl_xor(s, 2, 64);
        if (q == 0) y2s[r] = s;
    }
    __syncthreads();

    // ---- stage 4: dual-GEMM main loop, 4x4 register tile per thread ----
    const int ty = tid >> 4, tx = tid & 15;
    const int row0 = ty * 4, col0 = tx * 4;
    float axy[4][4] = {{0.f}}, axa[4][4] = {{0.f}};

    #pragma unroll
    for (int kk = 0; kk < TD; kk += 4) {
        float4 xq[4], pq[4], aq[4];
        #pragma unroll
        for (int j = 0; j < 4; ++j) xq[j] = *(const float4*)&Xs[row0 + j][kk];
        #pragma unroll
        for (int m = 0; m < 4; ++m) pq[m] = *(const float4*)&Ps[kk + m][col0];
        #pragma unroll
        for (int m = 0; m < 4; ++m) aq[m] = *(const float4*)&As[kk + m][col0];
        #pragma unroll
        for (int m = 0; m < 4; ++m) {
            const float* pf = (const float*)&pq[m];
            const float* af = (const float*)&aq[m];
            #pragma unroll
            for (int j = 0; j < 4; ++j) {
                const float xv = ((const float*)&xq[j])[m];
                #pragma unroll
                for (int i = 0; i < 4; ++i) {
                    axy[j][i] = fmaf(xv, pf[i], axy[j][i]);
                    axa[j][i] = fmaf(xv, af[i], axa[j][i]);
                }
            }
        }
    }

    // ---- stage 5: scalar epilogue + float32 store ----
    float y2v[4];
    #pragma unroll
    for (int j = 0; j < 4; ++j) y2v[j] = y2s[row0 + j];

    float x2c[4], pac[4], anc[4], scc[4], bec[4];
    #pragma unroll
    for (int i = 0; i < 4; ++i) {
        x2c[i] = x2s[col0 + i]; pac[i] = pas[col0 + i];
        anc[i] = ans[col0 + i]; scc[i] = scs[col0 + i];
        bec[i] = 1.0f - KCURV * x2c[i];
    }

    #pragma unroll
    for (int j = 0; j < 4; ++j) {
        int gr = rb + row0 + j;
        if (gr >= B) continue;
        float ov[4];
        #pragma unroll
        for (int i = 0; i < 4; ++i) {
            float xy = axy[j][i], xa = axa[j][i];
            float y2 = y2v[j];
            float x2 = x2c[i], beta = bec[i];
            float alpha = 1.0f + 2.0f * KCURV * xy + KCURV * y2;
            float den = 1.0f + 2.0f * KCURV * xy + (KCURV * KCURV) * x2 * y2;
            float rden = 1.0f / den;
            float g = (alpha * pac[i] + beta * xa) * rden;
            float numer = 2.0f * SQRT_K * g;
            float mob2 = (alpha * alpha * x2 + 2.0f * alpha * beta * xy
                          + beta * beta * y2) * (rden * rden);
            float denom = anc[i] * (1.0f - KCURV * mob2);
            ov[i] = scc[i] * asinhf(numer / denom);
        }
        int gc0 = cb + col0;
        float* orow = out + (size_t)gr * C + gc0;
        if (gc0 + 4 <= C) {
            *(float4*)orow = *(const float4*)ov;   // row base & offset 16B-aligned
        } else {
            for (int i = 0; i < 4; ++i)
                if (gc0 + i < C) orow[i] = ov[i];
        }
    }
}

extern "C" void kernel_launch(void* const* d_in, const int* in_sizes, int n_in,
                              void* d_out, int out_size, void* d_ws, size_t ws_size,
                              hipStream_t stream) {
    const float* x      = (const float*)d_in[0];
    const float* a_vals = (const float*)d_in[1];
    const float* p_vals = (const float*)d_in[2];
    int B = in_sizes[0] / TD;
    int C = in_sizes[1] / TD;
    dim3 grid((C + BN - 1) / BN, (B + BM - 1) / BM);
    hyper_mlr_kernel<<<grid, dim3(256), 0, stream>>>(
        x, a_vals, p_vals, (float*)d_out, B, C);
}

// Round 3
// 78.966 us; speedup vs baseline: 2.4497x; 2.4497x over previous
//
#include <hip/hip_runtime.h>
#include <hip/hip_bf16.h>
#include <math.h>

#define KCURV  0.1f
#define SQRT_K 0.31622776601683794f
#define INV_SQRT_K 3.1622776601683795f
#define TD 64   // feature dim D
#define BM 64   // batch rows per block
#define BN 64   // classes per block
#define LDP 68  // padded LDS row stride (floats), 272B = 16B aligned

__global__ __launch_bounds__(256) void hyper_mlr_kernel(
    const float* __restrict__ x,       // [B,64]
    const float* __restrict__ a_vals,  // [C,64]
    const float* __restrict__ p_vals,  // [C,64]
    float* __restrict__ out,           // [B,C] float32
    int B, int C)
{
    __shared__ float Xs[BM][LDP];   // [row][k]   raw x
    __shared__ float Ps[TD][LDP];   // [k][cls]   mp = -p_poin
    __shared__ float As[TD][LDP];   // [k][cls]   a_poin
    __shared__ float x2s[BN], pas[BN], ans[BN], scs[BN], y2s[BM];

    const int tid = threadIdx.x;
    const int cb = blockIdx.x * BN;
    const int rb = blockIdx.y * BM;

    // ---- stage 1: X tile global -> LDS (row-major, coalesced float4) ----
    #pragma unroll 1
    for (int t = 0; t < 4; ++t) {
        int idx = t * 256 + tid;        // 0..1023 float4 slots (64 rows x 16)
        int row = idx >> 4;
        int c4  = idx & 15;
        int gr = rb + row; if (gr >= B) gr = B - 1;
        float4 v = *(const float4*)(x + (size_t)gr * TD + c4 * 4);
        *(float4*)&Xs[row][c4 * 4] = v;
    }

    // ---- stage 2: per-class hyperbolic transform (4 lanes per class) ----
    {
        int c = tid >> 2;           // local class 0..63
        int q = tid & 3;            // quarter of the D dimension
        int gc = cb + c; if (gc >= C) gc = C - 1;
        const float* pr = p_vals + (size_t)gc * TD + q * 16;
        const float* ar = a_vals + (size_t)gc * TD + q * 16;
        float s_pp = 0.f, s_aa = 0.f, s_pa = 0.f;
        #pragma unroll 1
        for (int m = 0; m < 4; ++m) {
            float4 pv = *(const float4*)(pr + m * 4);
            float4 av = *(const float4*)(ar + m * 4);
            const float* pf = (const float*)&pv;
            const float* af = (const float*)&av;
            #pragma unroll
            for (int u = 0; u < 4; ++u) {
                s_pp = fmaf(pf[u], pf[u], s_pp);
                s_aa = fmaf(af[u], af[u], s_aa);
                s_pa = fmaf(pf[u], af[u], s_pa);
            }
        }
        // reduce across the 4-lane group (lanes 4c+q, q=0..3)
        s_pp += __shfl_xor(s_pp, 1, 64); s_pp += __shfl_xor(s_pp, 2, 64);
        s_aa += __shfl_xor(s_aa, 1, 64); s_aa += __shfl_xor(s_aa, 2, 64);
        s_pa += __shfl_xor(s_pa, 1, 64); s_pa += __shfl_xor(s_pa, 2, 64);

        float pn = sqrtf(s_pp); if (pn < 1e-15f) pn = 1e-15f;
        float arg = SQRT_K * pn;
        float t = tanhf(arg);
        float factor = t / arg;                 // p_poin = factor * p
        float p2 = factor * factor * s_pp;      // ||p_poin||^2  (== x2)
        float ca = 1.0f + KCURV * p2;           // a_poin = ca * a
        float anorm = ca * sqrtf(s_aa); if (anorm < 1e-15f) anorm = 1e-15f;
        float pa = -factor * ca * s_pa;         // sum(mp * a_poin)
        float lam = 2.0f / (1.0f - KCURV * p2);
        float scale = lam * anorm * INV_SQRT_K;

        if (q == 0) { x2s[c] = p2; pas[c] = pa; ans[c] = anorm; scs[c] = scale; }

        // write transformed operands K-major for vectorized LDS reads
        #pragma unroll 1
        for (int m = 0; m < 4; ++m) {
            float4 pv = *(const float4*)(pr + m * 4);
            float4 av = *(const float4*)(ar + m * 4);
            const float* pf = (const float*)&pv;
            const float* af = (const float*)&av;
            #pragma unroll
            for (int u = 0; u < 4; ++u) {
                int kk = q * 16 + m * 4 + u;
                Ps[kk][c] = -factor * pf[u];
                As[kk][c] = ca * af[u];
            }
        }
    }
    __syncthreads();

    // ---- stage 3: y2 per row (4 lanes per row, from LDS) ----
    {
        int r = tid >> 2, q = tid & 3;
        const float* xr = &Xs[r][q * 16];
        float s = 0.f;
        #pragma unroll
        for (int u = 0; u < 16; ++u) s = fmaf(xr[u], xr[u], s);
        s += __shfl_xor(s, 1, 64);
        s += __shfl_xor(s, 2, 64);
        if (q == 0) y2s[r] = s;
    }
    __syncthreads();

    // ---- stage 4: dual-GEMM main loop, 4x4 register tile per thread ----
    // NOTE: unroll 1 on kk is deliberate — full unroll made the scheduler
    // hoist 192 float4 LDS loads, VGPR hit the 256 cap, accumulators
    // spilled to scratch: 165 MB WRITE_SIZE / 318 MB FETCH_SIZE, 140 us.
    const int ty = tid >> 4, tx = tid & 15;
    const int row0 = ty * 4, col0 = tx * 4;
    float axy[4][4] = {{0.f}}, axa[4][4] = {{0.f}};

    #pragma unroll 1
    for (int kk = 0; kk < TD; kk += 4) {
        float4 pq[4], aq[4];
        #pragma unroll
        for (int m = 0; m < 4; ++m) pq[m] = *(const float4*)&Ps[kk + m][col0];
        #pragma unroll
        for (int m = 0; m < 4; ++m) aq[m] = *(const float4*)&As[kk + m][col0];
        #pragma unroll
        for (int j = 0; j < 4; ++j) {
            float4 xq = *(const float4*)&Xs[row0 + j][kk];
            const float* xf = (const float*)&xq;
            #pragma unroll
            for (int m = 0; m < 4; ++m) {
                const float xv = xf[m];
                const float* pf = (const float*)&pq[m];
                const float* af = (const float*)&aq[m];
                #pragma unroll
                for (int i = 0; i < 4; ++i) {
                    axy[j][i] = fmaf(xv, pf[i], axy[j][i]);
                    axa[j][i] = fmaf(xv, af[i], axa[j][i]);
                }
            }
        }
    }

    // ---- stage 5: scalar epilogue + float32 store ----
    float x2c[4], pac[4], anc[4], scc[4], bec[4];
    #pragma unroll
    for (int i = 0; i < 4; ++i) {
        x2c[i] = x2s[col0 + i]; pac[i] = pas[col0 + i];
        anc[i] = ans[col0 + i]; scc[i] = scs[col0 + i];
        bec[i] = 1.0f - KCURV * x2c[i];
    }

    #pragma unroll 1
    for (int j = 0; j < 4; ++j) {
        int gr = rb + row0 + j;
        if (gr >= B) continue;
        float y2 = y2s[row0 + j];
        float ov[4];
        #pragma unroll
        for (int i = 0; i < 4; ++i) {
            float xy = axy[j][i], xa = axa[j][i];
            float x2 = x2c[i], beta = bec[i];
            float alpha = 1.0f + 2.0f * KCURV * xy + KCURV * y2;
            float den = 1.0f + 2.0f * KCURV * xy + (KCURV * KCURV) * x2 * y2;
            float rden = 1.0f / den;
            float g = (alpha * pac[i] + beta * xa) * rden;
            float numer = 2.0f * SQRT_K * g;
            float mob2 = (alpha * alpha * x2 + 2.0f * alpha * beta * xy
                          + beta * beta * y2) * (rden * rden);
            float denom = anc[i] * (1.0f - KCURV * mob2);
            ov[i] = scc[i] * asinhf(numer / denom);
        }
        int gc0 = cb + col0;
        float* orow = out + (size_t)gr * C + gc0;
        if (gc0 + 4 <= C) {
            *(float4*)orow = *(const float4*)ov;   // row base & offset 16B-aligned
        } else {
            for (int i = 0; i < 4; ++i)
                if (gc0 + i < C) orow[i] = ov[i];
        }
    }
}

extern "C" void kernel_launch(void* const* d_in, const int* in_sizes, int n_in,
                              void* d_out, int out_size, void* d_ws, size_t ws_size,
                              hipStream_t stream) {
    const float* x      = (const float*)d_in[0];
    const float* a_vals = (const float*)d_in[1];
    const float* p_vals = (const float*)d_in[2];
    int B = in_sizes[0] / TD;
    int C = in_sizes[1] / TD;
    dim3 grid((C + BN - 1) / BN, (B + BM - 1) / BM);
    hyper_mlr_kernel<<<grid, dim3(256), 0, stream>>>(
        x, a_vals, p_vals, (float*)d_out, B, C);
}

// Round 4
// 73.257 us; speedup vs baseline: 2.6406x; 1.0779x over previous
//
#include <hip/hip_runtime.h>
#include <hip/hip_bf16.h>
#include <math.h>

#define KCURV  0.1f
#define SQRT_K 0.31622776601683794f
#define INV_SQRT_K 3.1622776601683795f
#define TD 64   // feature dim D
#define BM 64   // batch rows per block
#define BN 64   // classes per block
#define LDK 72  // padded LDS row stride in bf16 elems (144 B, 16B-aligned)

typedef __bf16  bf16x8  __attribute__((ext_vector_type(8)));
typedef float   f32x4   __attribute__((ext_vector_type(4)));

__device__ __forceinline__ unsigned short f2bf(float f) {
    __hip_bfloat16 h = __float2bfloat16(f);
    return *(unsigned short*)&h;
}

__global__ __launch_bounds__(256) void hyper_mlr_kernel(
    const float* __restrict__ x,       // [B,64]
    const float* __restrict__ a_vals,  // [C,64]
    const float* __restrict__ p_vals,  // [C,64]
    float* __restrict__ out,           // [B,C] float32
    int B, int C)
{
    // bf16 operand tiles, [row][k] / [class][k], k-contiguous for MFMA frags
    __shared__ unsigned short Xb[BM][LDK];
    __shared__ unsigned short Pb[BN][LDK];   // mp = -p_poin
    __shared__ unsigned short Ab[BN][LDK];   // a_poin
    __shared__ float x2s[BN], pas[BN], ans[BN], scs[BN], y2s[BM];

    const int tid = threadIdx.x;
    const int cb = blockIdx.x * BN;
    const int rb = blockIdx.y * BM;

    // ---- stage 1: X -> bf16 LDS + y2 (4 lanes per row, 16 k each) ----
    {
        int row = tid >> 2, q = tid & 3;
        int gr = rb + row; if (gr >= B) gr = B - 1;
        const float* xr = x + (size_t)gr * TD + q * 16;
        float v[16];
        #pragma unroll
        for (int m = 0; m < 4; ++m)
            *(float4*)&v[m * 4] = *(const float4*)(xr + m * 4);
        float s = 0.f;
        #pragma unroll
        for (int u = 0; u < 16; ++u) s = fmaf(v[u], v[u], s);
        s += __shfl_xor(s, 1, 64);
        s += __shfl_xor(s, 2, 64);
        if (q == 0) y2s[row] = s;
        unsigned short ub[16];
        #pragma unroll
        for (int u = 0; u < 16; ++u) ub[u] = f2bf(v[u]);
        *(ulonglong2*)&Xb[row][q * 16]     = *(const ulonglong2*)&ub[0];
        *(ulonglong2*)&Xb[row][q * 16 + 8] = *(const ulonglong2*)&ub[8];
    }

    // ---- stage 2: per-class hyperbolic transform (4 lanes per class) ----
    {
        int c = tid >> 2, q = tid & 3;
        int gc = cb + c; if (gc >= C) gc = C - 1;
        const float* pr = p_vals + (size_t)gc * TD + q * 16;
        const float* ar = a_vals + (size_t)gc * TD + q * 16;
        float pv[16], av[16];
        #pragma unroll
        for (int m = 0; m < 4; ++m) {
            *(float4*)&pv[m * 4] = *(const float4*)(pr + m * 4);
            *(float4*)&av[m * 4] = *(const float4*)(ar + m * 4);
        }
        float s_pp = 0.f, s_aa = 0.f;
        #pragma unroll
        for (int u = 0; u < 16; ++u) {
            s_pp = fmaf(pv[u], pv[u], s_pp);
            s_aa = fmaf(av[u], av[u], s_aa);
        }
        s_pp += __shfl_xor(s_pp, 1, 64); s_pp += __shfl_xor(s_pp, 2, 64);
        s_aa += __shfl_xor(s_aa, 1, 64); s_aa += __shfl_xor(s_aa, 2, 64);

        float pn = sqrtf(s_pp); if (pn < 1e-15f) pn = 1e-15f;
        float arg = SQRT_K * pn;
        float t = tanhf(arg);
        float factor = t / arg;                 // p_poin = factor * p
        float p2 = factor * factor * s_pp;      // ||p_poin||^2
        float ca = 1.0f + KCURV * p2;           // a_poin = ca * a
        float anorm = ca * sqrtf(s_aa); if (anorm < 1e-15f) anorm = 1e-15f;
        float lam = 2.0f / (1.0f - KCURV * p2);
        float scale = lam * anorm * INV_SQRT_K;

        // pa = sum(mp * a_poin) in fp32 (4-lane reduce)
        float s_pa = 0.f;
        #pragma unroll
        for (int u = 0; u < 16; ++u) s_pa = fmaf(pv[u], av[u], s_pa);
        s_pa += __shfl_xor(s_pa, 1, 64); s_pa += __shfl_xor(s_pa, 2, 64);
        float pa = -factor * ca * s_pa;

        if (q == 0) { x2s[c] = p2; pas[c] = pa; ans[c] = anorm; scs[c] = scale; }

        unsigned short ubp[16], uba[16];
        #pragma unroll
        for (int u = 0; u < 16; ++u) {
            ubp[u] = f2bf(-factor * pv[u]);
            uba[u] = f2bf(ca * av[u]);
        }
        *(ulonglong2*)&Pb[c][q * 16]     = *(const ulonglong2*)&ubp[0];
        *(ulonglong2*)&Pb[c][q * 16 + 8] = *(const ulonglong2*)&ubp[8];
        *(ulonglong2*)&Ab[c][q * 16]     = *(const ulonglong2*)&uba[0];
        *(ulonglong2*)&Ab[c][q * 16 + 8] = *(const ulonglong2*)&uba[8];
    }
    __syncthreads();

    // ---- stage 3: MFMA dual-GEMM. wave w -> rows 16w..16w+15, all 64 cols.
    // A-frag: A[m=lane&15][k=quad*8+j]; B-frag: B[k=quad*8+j][n=lane&15];
    // C/D: col=lane&15, row=quad*4+reg  (m89/m120-verified layouts)
    const int w    = tid >> 6;
    const int lane = tid & 63;
    const int m16  = lane & 15;
    const int quad = lane >> 4;

    f32x4 accP[4], accA[4];
    #pragma unroll
    for (int t = 0; t < 4; ++t) {
        accP[t] = (f32x4){0.f, 0.f, 0.f, 0.f};
        accA[t] = (f32x4){0.f, 0.f, 0.f, 0.f};
    }

    #pragma unroll
    for (int step = 0; step < 2; ++step) {
        const int ko = quad * 8 + step * 32;
        bf16x8 af = *(const bf16x8*)&Xb[16 * w + m16][ko];
        #pragma unroll
        for (int t = 0; t < 4; ++t) {
            bf16x8 bp = *(const bf16x8*)&Pb[16 * t + m16][ko];
            bf16x8 ba = *(const bf16x8*)&Ab[16 * t + m16][ko];
            accP[t] = __builtin_amdgcn_mfma_f32_16x16x32_bf16(af, bp, accP[t], 0, 0, 0);
            accA[t] = __builtin_amdgcn_mfma_f32_16x16x32_bf16(af, ba, accA[t], 0, 0, 0);
        }
    }

    // ---- stage 4: epilogue + store ----
    #pragma unroll
    for (int t = 0; t < 4; ++t) {
        const int cl = 16 * t + m16;          // local class
        const int gc = cb + cl;
        const float x2 = x2s[cl], pa = pas[cl], an = ans[cl], sc = scs[cl];
        const float beta = 1.0f - KCURV * x2;
        #pragma unroll
        for (int r = 0; r < 4; ++r) {
            const int rl = 16 * w + quad * 4 + r;  // local row
            const int gr = rb + rl;
            const float y2 = y2s[rl];
            const float xy = accP[t][r];
            const float xa = accA[t][r];
            float alpha = 1.0f + 2.0f * KCURV * xy + KCURV * y2;
            float den = 1.0f + 2.0f * KCURV * xy + (KCURV * KCURV) * x2 * y2;
            float rden = 1.0f / den;
            float numer = 2.0f * SQRT_K * (alpha * pa + beta * xa) * rden;
            float mob2 = (alpha * alpha * x2 + 2.0f * alpha * beta * xy
                          + beta * beta * y2) * (rden * rden);
            float denom = an * (1.0f - KCURV * mob2);
            float lg = sc * asinhf(numer / denom);
            if (gr < B && gc < C) out[(size_t)gr * C + gc] = lg;
        }
    }
}

extern "C" void kernel_launch(void* const* d_in, const int* in_sizes, int n_in,
                              void* d_out, int out_size, void* d_ws, size_t ws_size,
                              hipStream_t stream) {
    const float* x      = (const float*)d_in[0];
    const float* a_vals = (const float*)d_in[1];
    const float* p_vals = (const float*)d_in[2];
    int B = in_sizes[0] / TD;
    int C = in_sizes[1] / TD;
    dim3 grid((C + BN - 1) / BN, (B + BM - 1) / BM);
    hyper_mlr_kernel<<<grid, dim3(256), 0, stream>>>(
        x, a_vals, p_vals, (float*)d_out, B, C);
}

// Round 5
// 69.441 us; speedup vs baseline: 2.7857x; 1.0549x over previous
//
#include <hip/hip_runtime.h>
#include <hip/hip_bf16.h>
#include <math.h>

#define KCURV  0.1f
#define KK     0.010000001f          // k*k
#define SQRT_K 0.31622776601683794f
#define TWO_SQRT_K 0.6324555320336759f
#define INV_SQRT_K 3.1622776601683795f
#define TD 64   // feature dim D

typedef __bf16  bf16x8  __attribute__((ext_vector_type(8)));
typedef float   f32x4   __attribute__((ext_vector_type(4)));

__device__ __forceinline__ unsigned short f2bf(float f) {
    __hip_bfloat16 h = __float2bfloat16(f);
    return *(unsigned short*)&h;
}

// ---------------- kernel 1: operand prep (tiny, latency-bound) -------------
// blocks [0, rowBlocks): rows -> Xbf (bf16) + y2
// blocks [rowBlocks, rowBlocks+clsBlocks): classes -> Pbf/Abf (bf16) + scalars
__global__ __launch_bounds__(256) void prep_kernel(
    const float* __restrict__ x, const float* __restrict__ a_vals,
    const float* __restrict__ p_vals,
    unsigned short* __restrict__ Xbf, unsigned short* __restrict__ Pbf,
    unsigned short* __restrict__ Abf,
    float* __restrict__ y2g, float* __restrict__ x2g, float* __restrict__ pag,
    float* __restrict__ ang, float* __restrict__ scg,
    int B, int C, int rowBlocks)
{
    const int tid = threadIdx.x;
    const int item = (blockIdx.x < rowBlocks ? blockIdx.x
                                             : blockIdx.x - rowBlocks) * 64 + (tid >> 2);
    const int q = tid & 3;

    if (blockIdx.x < rowBlocks) {
        int gr = item < B ? item : B - 1;
        const float* xr = x + (size_t)gr * TD + q * 16;
        float v[16];
        #pragma unroll
        for (int m = 0; m < 4; ++m)
            *(float4*)&v[m * 4] = *(const float4*)(xr + m * 4);
        float s = 0.f;
        #pragma unroll
        for (int u = 0; u < 16; ++u) s = fmaf(v[u], v[u], s);
        s += __shfl_xor(s, 1, 64);
        s += __shfl_xor(s, 2, 64);
        if (q == 0) y2g[item] = s;
        unsigned short ub[16];
        #pragma unroll
        for (int u = 0; u < 16; ++u) ub[u] = f2bf(v[u]);
        unsigned short* dst = Xbf + (size_t)item * TD + q * 16;
        *(ulonglong2*)dst       = *(const ulonglong2*)&ub[0];
        *(ulonglong2*)(dst + 8) = *(const ulonglong2*)&ub[8];
    } else {
        int gc = item < C ? item : C - 1;   // pad classes with a clamped copy
        const float* pr = p_vals + (size_t)gc * TD + q * 16;
        const float* ar = a_vals + (size_t)gc * TD + q * 16;
        float pv[16], av[16];
        #pragma unroll
        for (int m = 0; m < 4; ++m) {
            *(float4*)&pv[m * 4] = *(const float4*)(pr + m * 4);
            *(float4*)&av[m * 4] = *(const float4*)(ar + m * 4);
        }
        float s_pp = 0.f, s_aa = 0.f, s_pa = 0.f;
        #pragma unroll
        for (int u = 0; u < 16; ++u) {
            s_pp = fmaf(pv[u], pv[u], s_pp);
            s_aa = fmaf(av[u], av[u], s_aa);
            s_pa = fmaf(pv[u], av[u], s_pa);
        }
        s_pp += __shfl_xor(s_pp, 1, 64); s_pp += __shfl_xor(s_pp, 2, 64);
        s_aa += __shfl_xor(s_aa, 1, 64); s_aa += __shfl_xor(s_aa, 2, 64);
        s_pa += __shfl_xor(s_pa, 1, 64); s_pa += __shfl_xor(s_pa, 2, 64);

        float pn = sqrtf(s_pp); if (pn < 1e-15f) pn = 1e-15f;
        float arg = SQRT_K * pn;
        float t = tanhf(arg);
        float factor = t / arg;                 // p_poin = factor * p
        float p2 = factor * factor * s_pp;      // ||p_poin||^2
        float ca = 1.0f + KCURV * p2;           // a_poin = ca * a
        float anorm = ca * sqrtf(s_aa); if (anorm < 1e-15f) anorm = 1e-15f;
        float lam = 2.0f / (1.0f - KCURV * p2);
        float scale = lam * anorm * INV_SQRT_K;
        float pa = -factor * ca * s_pa;         // sum(mp * a_poin)

        if (q == 0) {
            x2g[item] = p2; pag[item] = pa; ang[item] = anorm; scg[item] = scale;
        }
        unsigned short ubp[16], uba[16];
        #pragma unroll
        for (int u = 0; u < 16; ++u) {
            ubp[u] = f2bf(-factor * pv[u]);
            uba[u] = f2bf(ca * av[u]);
        }
        unsigned short* dp = Pbf + (size_t)item * TD + q * 16;
        unsigned short* da = Abf + (size_t)item * TD + q * 16;
        *(ulonglong2*)dp       = *(const ulonglong2*)&ubp[0];
        *(ulonglong2*)(dp + 8) = *(const ulonglong2*)&ubp[8];
        *(ulonglong2*)da       = *(const ulonglong2*)&uba[0];
        *(ulonglong2*)(da + 8) = *(const ulonglong2*)&uba[8];
    }
}

// ---------------- kernel 2: LDS-free MFMA dual-GEMM + epilogue -------------
// wave w -> rows rb+16w..+15, all 64 classes of the tile. No LDS, no barriers:
// fragments loaded straight global->register (L2-hot bf16 operands).
__global__ __launch_bounds__(256) void mlr_gemm_kernel(
    const unsigned short* __restrict__ Xbf, const unsigned short* __restrict__ Pbf,
    const unsigned short* __restrict__ Abf,
    const float* __restrict__ y2g, const float* __restrict__ x2g,
    const float* __restrict__ pag, const float* __restrict__ ang,
    const float* __restrict__ scg,
    float* __restrict__ out, int B, int C)
{
    const int tid  = threadIdx.x;
    const int w    = tid >> 6;
    const int lane = tid & 63;
    const int m16  = lane & 15;
    const int quad = lane >> 4;
    const int cb   = blockIdx.x * 64;
    const int rb   = blockIdx.y * 64;
    const int arow = rb + 16 * w + m16;

    // A-frag: A[m=lane&15][k=quad*8+j]; B-frag same addressing on class rows;
    // C/D: col=lane&15, row=quad*4+reg  (validated end-to-end in round 4)
    bf16x8 af[2], bp[4][2], ba[4][2];
    #pragma unroll
    for (int step = 0; step < 2; ++step) {
        const int ko = quad * 8 + step * 32;
        af[step] = *(const bf16x8*)(Xbf + (size_t)arow * TD + ko);
        #pragma unroll
        for (int t = 0; t < 4; ++t) {
            const size_t crow = (size_t)(cb + 16 * t + m16) * TD + ko;
            bp[t][step] = *(const bf16x8*)(Pbf + crow);
            ba[t][step] = *(const bf16x8*)(Abf + crow);
        }
    }

    f32x4 accP[4], accA[4];
    #pragma unroll
    for (int t = 0; t < 4; ++t) {
        accP[t] = (f32x4){0.f, 0.f, 0.f, 0.f};
        accA[t] = (f32x4){0.f, 0.f, 0.f, 0.f};
    }
    #pragma unroll
    for (int step = 0; step < 2; ++step) {
        #pragma unroll
        for (int t = 0; t < 4; ++t) {
            accP[t] = __builtin_amdgcn_mfma_f32_16x16x32_bf16(af[step], bp[t][step], accP[t], 0, 0, 0);
            accA[t] = __builtin_amdgcn_mfma_f32_16x16x32_bf16(af[step], ba[t][step], accA[t], 0, 0, 0);
        }
    }

    // per-row values (quad*4 is 16B aligned -> one dwordx4)
    const float4 y2v = *(const float4*)(y2g + rb + 16 * w + quad * 4);
    const float* y2p = (const float*)&y2v;

    #pragma unroll
    for (int t = 0; t < 4; ++t) {
        const int cl = cb + 16 * t + m16;
        const float x2 = x2g[cl], pa = pag[cl], an = ang[cl], sc = scg[cl];
        const float beta = 1.0f - KCURV * x2;
        const float kkx2 = KK * x2;
        #pragma unroll
        for (int r = 0; r < 4; ++r) {
            const int gr = rb + 16 * w + quad * 4 + r;
            const float y2 = y2p[r];
            const float xy = accP[t][r];
            const float xa = accA[t][r];
            float t1    = fmaf(2.0f * KCURV, xy, 1.0f);
            float den   = fmaf(kkx2, y2, t1);                 // mobius denom
            float alpha = fmaf(KCURV, y2, t1);
            float g     = fmaf(alpha, pa, beta * xa);
            float M     = fmaf(alpha * alpha, x2,
                          fmaf(2.0f * alpha * beta, xy, beta * beta * y2));
            // z = numer/denom with a single reciprocal:
            // numer = 2√k·g/den ; denom = an·(1 - k·M/den²)
            // => z = 2√k·g·den / (an·(den² - k·M))
            float dd    = fmaf(den, den, -KCURV * M);
            float z     = TWO_SQRT_K * g * den * __builtin_amdgcn_rcpf(an * dd);
            float lg    = sc * __logf(z + sqrtf(fmaf(z, z, 1.0f)));   // asinh
            if (cl < C) out[(size_t)gr * C + cl] = lg;
        }
    }
}

extern "C" void kernel_launch(void* const* d_in, const int* in_sizes, int n_in,
                              void* d_out, int out_size, void* d_ws, size_t ws_size,
                              hipStream_t stream) {
    const float* x      = (const float*)d_in[0];
    const float* a_vals = (const float*)d_in[1];
    const float* p_vals = (const float*)d_in[2];
    const int B = in_sizes[0] / TD;
    const int C = in_sizes[1] / TD;
    const int rowBlocks = (B + 63) / 64;
    const int clsBlocks = (C + 63) / 64;
    const int CPAD = clsBlocks * 64;

    char* ws = (char*)d_ws;
    unsigned short* Xbf = (unsigned short*)ws;
    unsigned short* Pbf = (unsigned short*)(ws + (size_t)B * TD * 2);
    unsigned short* Abf = (unsigned short*)(ws + (size_t)B * TD * 2 + (size_t)CPAD * TD * 2);
    float* y2g = (float*)(ws + (size_t)B * TD * 2 + (size_t)CPAD * TD * 4);
    float* x2g = y2g + B;
    float* pag = x2g + CPAD;
    float* ang = pag + CPAD;
    float* scg = ang + CPAD;

    prep_kernel<<<rowBlocks + clsBlocks, 256, 0, stream>>>(
        x, a_vals, p_vals, Xbf, Pbf, Abf, y2g, x2g, pag, ang, scg, B, C, rowBlocks);

    dim3 grid(clsBlocks, rowBlocks);
    mlr_gemm_kernel<<<grid, dim3(256), 0, stream>>>(
        Xbf, Pbf, Abf, y2g, x2g, pag, ang, scg, (float*)d_out, B, C);
}

// Round 6
// 69.390 us; speedup vs baseline: 2.7877x; 1.0007x over previous
//
#include <hip/hip_runtime.h>
#include <hip/hip_bf16.h>
#include <math.h>

#define KCURV  0.1f
#define KK     0.010000001f          // k*k
#define SQRT_K 0.31622776601683794f
#define TWO_SQRT_K 0.6324555320336759f
#define INV_SQRT_K 3.1622776601683795f
#define TD 64   // feature dim D

typedef __bf16  bf16x8  __attribute__((ext_vector_type(8)));
typedef float   f32x4   __attribute__((ext_vector_type(4)));

__device__ __forceinline__ unsigned short f2bf(float f) {
    __hip_bfloat16 h = __float2bfloat16(f);
    return *(unsigned short*)&h;
}

// ---------------- kernel 1: class-operand prep (16 blocks, latency-bound) --
// classes -> Pbf/Abf (bf16, row-major k-contiguous) + per-class scalars
__global__ __launch_bounds__(256) void prep_kernel(
    const float* __restrict__ a_vals, const float* __restrict__ p_vals,
    unsigned short* __restrict__ Pbf, unsigned short* __restrict__ Abf,
    float* __restrict__ x2g, float* __restrict__ pag,
    float* __restrict__ ang, float* __restrict__ scg,
    int C)
{
    const int tid  = threadIdx.x;
    const int item = blockIdx.x * 64 + (tid >> 2);
    const int q    = tid & 3;
    const int gc   = item < C ? item : C - 1;   // pad tail with clamped copy

    const float* pr = p_vals + (size_t)gc * TD + q * 16;
    const float* ar = a_vals + (size_t)gc * TD + q * 16;
    float pv[16], av[16];
    #pragma unroll
    for (int m = 0; m < 4; ++m) {
        *(float4*)&pv[m * 4] = *(const float4*)(pr + m * 4);
        *(float4*)&av[m * 4] = *(const float4*)(ar + m * 4);
    }
    float s_pp = 0.f, s_aa = 0.f, s_pa = 0.f;
    #pragma unroll
    for (int u = 0; u < 16; ++u) {
        s_pp = fmaf(pv[u], pv[u], s_pp);
        s_aa = fmaf(av[u], av[u], s_aa);
        s_pa = fmaf(pv[u], av[u], s_pa);
    }
    s_pp += __shfl_xor(s_pp, 1, 64); s_pp += __shfl_xor(s_pp, 2, 64);
    s_aa += __shfl_xor(s_aa, 1, 64); s_aa += __shfl_xor(s_aa, 2, 64);
    s_pa += __shfl_xor(s_pa, 1, 64); s_pa += __shfl_xor(s_pa, 2, 64);

    float pn = sqrtf(s_pp); if (pn < 1e-15f) pn = 1e-15f;
    float arg = SQRT_K * pn;
    float t = tanhf(arg);
    float factor = t / arg;                 // p_poin = factor * p
    float p2 = factor * factor * s_pp;      // ||p_poin||^2
    float ca = 1.0f + KCURV * p2;           // a_poin = ca * a
    float anorm = ca * sqrtf(s_aa); if (anorm < 1e-15f) anorm = 1e-15f;
    float lam = 2.0f / (1.0f - KCURV * p2);
    float scale = lam * anorm * INV_SQRT_K;
    float pa = -factor * ca * s_pa;         // sum(mp * a_poin)

    if (q == 0) {
        x2g[item] = p2; pag[item] = pa; ang[item] = anorm; scg[item] = scale;
    }
    unsigned short ubp[16], uba[16];
    #pragma unroll
    for (int u = 0; u < 16; ++u) {
        ubp[u] = f2bf(-factor * pv[u]);
        uba[u] = f2bf(ca * av[u]);
    }
    unsigned short* dp = Pbf + (size_t)item * TD + q * 16;
    unsigned short* da = Abf + (size_t)item * TD + q * 16;
    *(ulonglong2*)dp       = *(const ulonglong2*)&ubp[0];
    *(ulonglong2*)(dp + 8) = *(const ulonglong2*)&ubp[8];
    *(ulonglong2*)da       = *(const ulonglong2*)&uba[0];
    *(ulonglong2*)(da + 8) = *(const ulonglong2*)&uba[8];
}

// ---------------- kernel 2: LDS-free MFMA dual-GEMM + epilogue -------------
// wave w -> rows rb+16w..+15, all 64 classes of the tile. No LDS, no
// barriers. X is read as raw fp32 (independent of prep), converted to bf16
// in-register; y2 computed in-wave: lanes sharing m16 jointly hold all 64 k
// of their A-row, so Σv² + shfl_xor(16,32) = exact fp32 row norm.
__global__ __launch_bounds__(256) void mlr_gemm_kernel(
    const float* __restrict__ x,
    const unsigned short* __restrict__ Pbf, const unsigned short* __restrict__ Abf,
    const float* __restrict__ x2g, const float* __restrict__ pag,
    const float* __restrict__ ang, const float* __restrict__ scg,
    float* __restrict__ out, int B, int C)
{
    const int tid  = threadIdx.x;
    const int w    = tid >> 6;
    const int lane = tid & 63;
    const int m16  = lane & 15;
    const int quad = lane >> 4;
    const int cb   = blockIdx.x * 64;
    const int rb   = blockIdx.y * 64;
    int arow = rb + 16 * w + m16; if (arow >= B) arow = B - 1;

    // A-frag: A[m=lane&15][k=quad*8+j]; B-frag same addressing on class rows;
    // C/D: col=lane&15, row=quad*4+reg  (validated end-to-end in rounds 4/5)
    float xv[2][8];
    bf16x8 bp[4][2], ba[4][2];
    #pragma unroll
    for (int step = 0; step < 2; ++step) {
        const int ko = quad * 8 + step * 32;
        const float* xr = x + (size_t)arow * TD + ko;
        *(float4*)&xv[step][0] = *(const float4*)xr;
        *(float4*)&xv[step][4] = *(const float4*)(xr + 4);
        #pragma unroll
        for (int t = 0; t < 4; ++t) {
            const size_t crow = (size_t)(cb + 16 * t + m16) * TD + ko;
            bp[t][step] = *(const bf16x8*)(Pbf + crow);
            ba[t][step] = *(const bf16x8*)(Abf + crow);
        }
    }

    // y2: exact fp32 row norms, then rebroadcast to C-layout rows
    float s = 0.f;
    #pragma unroll
    for (int step = 0; step < 2; ++step)
        #pragma unroll
        for (int u = 0; u < 8; ++u) s = fmaf(xv[step][u], xv[step][u], s);
    s += __shfl_xor(s, 16, 64);
    s += __shfl_xor(s, 32, 64);
    float y2r[4];
    #pragma unroll
    for (int r = 0; r < 4; ++r) y2r[r] = __shfl(s, quad * 4 + r, 64);

    // fp32 -> bf16 A-fragments
    bf16x8 af[2];
    #pragma unroll
    for (int step = 0; step < 2; ++step) {
        union { unsigned short u[8]; bf16x8 v; } cv;
        #pragma unroll
        for (int u = 0; u < 8; ++u) cv.u[u] = f2bf(xv[step][u]);
        af[step] = cv.v;
    }

    f32x4 accP[4], accA[4];
    #pragma unroll
    for (int t = 0; t < 4; ++t) {
        accP[t] = (f32x4){0.f, 0.f, 0.f, 0.f};
        accA[t] = (f32x4){0.f, 0.f, 0.f, 0.f};
    }
    #pragma unroll
    for (int step = 0; step < 2; ++step) {
        #pragma unroll
        for (int t = 0; t < 4; ++t) {
            accP[t] = __builtin_amdgcn_mfma_f32_16x16x32_bf16(af[step], bp[t][step], accP[t], 0, 0, 0);
            accA[t] = __builtin_amdgcn_mfma_f32_16x16x32_bf16(af[step], ba[t][step], accA[t], 0, 0, 0);
        }
    }

    #pragma unroll
    for (int t = 0; t < 4; ++t) {
        const int cl = cb + 16 * t + m16;
        const float x2 = x2g[cl], pa = pag[cl], an = ang[cl], sc = scg[cl];
        const float beta = 1.0f - KCURV * x2;
        const float kkx2 = KK * x2;
        #pragma unroll
        for (int r = 0; r < 4; ++r) {
            const int gr = rb + 16 * w + quad * 4 + r;
            const float y2 = y2r[r];
            const float xy = accP[t][r];
            const float xa = accA[t][r];
            float t1    = fmaf(2.0f * KCURV, xy, 1.0f);
            float den   = fmaf(kkx2, y2, t1);                 // mobius denom
            float alpha = fmaf(KCURV, y2, t1);
            float g     = fmaf(alpha, pa, beta * xa);
            float M     = fmaf(alpha * alpha, x2,
                          fmaf(2.0f * alpha * beta, xy, beta * beta * y2));
            // z = 2√k·g·den / (an·(den² - k·M))  (single reciprocal)
            float dd    = fmaf(den, den, -KCURV * M);
            float z     = TWO_SQRT_K * g * den * __builtin_amdgcn_rcpf(an * dd);
            float lg    = sc * __logf(z + sqrtf(fmaf(z, z, 1.0f)));   // asinh
            if (cl < C && gr < B) out[(size_t)gr * C + cl] = lg;
        }
    }
}

extern "C" void kernel_launch(void* const* d_in, const int* in_sizes, int n_in,
                              void* d_out, int out_size, void* d_ws, size_t ws_size,
                              hipStream_t stream) {
    const float* x      = (const float*)d_in[0];
    const float* a_vals = (const float*)d_in[1];
    const float* p_vals = (const float*)d_in[2];
    const int B = in_sizes[0] / TD;
    const int C = in_sizes[1] / TD;
    const int rowBlocks = (B + 63) / 64;
    const int clsBlocks = (C + 63) / 64;
    const int CPAD = clsBlocks * 64;

    char* ws = (char*)d_ws;
    unsigned short* Pbf = (unsigned short*)ws;
    unsigned short* Abf = (unsigned short*)(ws + (size_t)CPAD * TD * 2);
    float* x2g = (float*)(ws + (size_t)CPAD * TD * 4);
    float* pag = x2g + CPAD;
    float* ang = pag + CPAD;
    float* scg = ang + CPAD;

    prep_kernel<<<clsBlocks, 256, 0, stream>>>(
        a_vals, p_vals, Pbf, Abf, x2g, pag, ang, scg, C);

    dim3 grid(clsBlocks, rowBlocks);
    mlr_gemm_kernel<<<grid, dim3(256), 0, stream>>>(
        x, Pbf, Abf, x2g, pag, ang, scg, (float*)d_out, B, C);
}